// Round 1
// baseline (715.947 us; speedup 1.0000x reference)
//
#include <hip/hip_runtime.h>
#include <cstdint>

#define B_ 4
#define S_ 2048
#define D_ 1024
#define H_ 16
#define DK_ 64

typedef unsigned short u16;
typedef __bf16 bf16x8 __attribute__((ext_vector_type(8)));
typedef float f32x4 __attribute__((ext_vector_type(4)));
typedef u16 u16x8 __attribute__((ext_vector_type(8)));

__device__ __forceinline__ u16 f2bf(float f) {
  union { float f; unsigned u; } x; x.f = f;
  unsigned r = (x.u + 0x7fffu + ((x.u >> 16) & 1u)) >> 16;  // RNE
  return (u16)r;
}

__device__ __forceinline__ bf16x8 ld_bf8(const u16* p) {
  u16x8 v = *(const u16x8*)p;
  return __builtin_bit_cast(bf16x8, v);
}

__device__ __forceinline__ f32x4 mfma16(bf16x8 a, bf16x8 b, f32x4 c) {
  return __builtin_amdgcn_mfma_f32_16x16x32_bf16(a, b, c, 0, 0, 0);
}

// async global->LDS, 16B per lane; dest is wave-uniform base + lane*16 (linear)
__device__ __forceinline__ void gload_lds16(const void* g, void* l) {
  __builtin_amdgcn_global_load_lds(
      (__attribute__((address_space(1))) void*)(void*)g,
      (__attribute__((address_space(3))) void*)l, 16, 0, 0);
}

// ---------------------------------------------------------------------------
// fp32 -> bf16 cast of q,k,v,Wq,Wk,Wv,Wo into workspace. 8 elems/thread.
// unit = 8 elems. q/k/v: 1048576 units each; each W: 131072 units.
__global__ void cast_bf16_all(const float* __restrict__ q, const float* __restrict__ k,
                              const float* __restrict__ v, const float* __restrict__ wq,
                              const float* __restrict__ wk, const float* __restrict__ wv,
                              const float* __restrict__ wo, u16* __restrict__ ws) {
  const size_t u = (size_t)blockIdx.x * blockDim.x + threadIdx.x;
  const float* src;
  size_t dstoff, rel;
  if (u < 3145728) {
    const size_t which = u >> 20;
    rel = u & 1048575;
    src = (which == 0) ? q : ((which == 1) ? k : v);
    dstoff = which * 8388608;
  } else {
    const size_t w = u - 3145728;
    const size_t which = w >> 17;
    rel = w & 131071;
    src = (which == 0) ? wq : ((which == 1) ? wk : ((which == 2) ? wv : wo));
    dstoff = 25165824 + which * 1048576;
  }
  const float4* s4 = (const float4*)(src + rel * 8);
  float4 a = s4[0], b = s4[1];
  u16x8 o;
  o[0] = f2bf(a.x); o[1] = f2bf(a.y); o[2] = f2bf(a.z); o[3] = f2bf(a.w);
  o[4] = f2bf(b.x); o[5] = f2bf(b.y); o[6] = f2bf(b.z); o[7] = f2bf(b.w);
  *(u16x8*)(ws + dstoff + rel * 8) = o;
}

// ---------------------------------------------------------------------------
// C[M,N] = A[M,K] * W[N,K]^T + bias, bf16 inputs, 128x128 tile, BK=64.
// mode 0: write bf16 to [B,H,S,DK] head layout
// mode 1: write bf16 to [B,H,DK,S] (transposed V)
// mode 2: write fp32 row-major [M,N]
__global__ __launch_bounds__(256, 2) void gemm_bt(
    const u16* __restrict__ A, const u16* __restrict__ W,
    const float* __restrict__ bias, void* __restrict__ out,
    int M, int N, int K, int mode) {
  __shared__ __align__(16) u16 sA[128 * 64];
  __shared__ __align__(16) u16 sB[128 * 64];
  const int t = threadIdx.x;
  const int lane = t & 63;
  const int wave = t >> 6;
  const int wr = (wave >> 1) * 64, wc = (wave & 1) * 64;
  const int m0 = blockIdx.x * 128, n0 = blockIdx.y * 128;
  const int l15 = lane & 15, lhi = lane >> 4;

  f32x4 acc[4][4];
#pragma unroll
  for (int i = 0; i < 4; ++i)
#pragma unroll
    for (int j = 0; j < 4; ++j) acc[i][j] = (f32x4){0.f, 0.f, 0.f, 0.f};

  const int sr = t >> 3;    // row within 32-row issue group
  const int slot = t & 7;   // 16B slot within 128B row

  for (int kt = 0; kt < K; kt += 64) {
    // stage A,B tiles: linear LDS dest, source chunk pre-swizzled (chunk = slot ^ (row&7))
#pragma unroll
    for (int i = 0; i < 4; ++i) {
      const int r = i * 32 + sr;
      const int c = slot ^ (r & 7);
      gload_lds16(A + (size_t)(m0 + r) * K + kt + c * 8, (char*)sA + (i * 4096 + t * 16));
      gload_lds16(W + (size_t)(n0 + r) * K + kt + c * 8, (char*)sB + (i * 4096 + t * 16));
    }
    __syncthreads();  // compiler drains vmcnt before s_barrier

    bf16x8 af[4][2], bfr[4][2];
#pragma unroll
    for (int mt = 0; mt < 4; ++mt) {
      const int r = wr + mt * 16 + l15;
#pragma unroll
      for (int ks = 0; ks < 2; ++ks) {
        const int ch = ks * 4 + lhi;
        af[mt][ks] = ld_bf8((const u16*)((const char*)sA + r * 128 + ((ch ^ (r & 7)) * 16)));
      }
    }
#pragma unroll
    for (int nt = 0; nt < 4; ++nt) {
      const int r = wc + nt * 16 + l15;
#pragma unroll
      for (int ks = 0; ks < 2; ++ks) {
        const int ch = ks * 4 + lhi;
        bfr[nt][ks] = ld_bf8((const u16*)((const char*)sB + r * 128 + ((ch ^ (r & 7)) * 16)));
      }
    }
#pragma unroll
    for (int mt = 0; mt < 4; ++mt)
#pragma unroll
      for (int nt = 0; nt < 4; ++nt) {
        acc[mt][nt] = mfma16(af[mt][0], bfr[nt][0], acc[mt][nt]);
        acc[mt][nt] = mfma16(af[mt][1], bfr[nt][1], acc[mt][nt]);
      }
    __syncthreads();
  }

  float bv[4];
#pragma unroll
  for (int nt = 0; nt < 4; ++nt) bv[nt] = bias[n0 + wc + nt * 16 + l15];

#pragma unroll
  for (int mt = 0; mt < 4; ++mt) {
#pragma unroll
    for (int nt = 0; nt < 4; ++nt) {
#pragma unroll
      for (int r = 0; r < 4; ++r) {
        const int gm = m0 + wr + mt * 16 + lhi * 4 + r;
        const int gn = n0 + wc + nt * 16 + l15;
        const float val = acc[mt][nt][r] + bv[nt];
        if (mode == 2) {
          ((float*)out)[(size_t)gm * N + gn] = val;
        } else {
          const int b = gm >> 11, s = gm & 2047, h = gn >> 6, dk = gn & 63;
          size_t addr;
          if (mode == 0) addr = (((size_t)b * H_ + h) * S_ + s) * DK_ + dk;
          else           addr = (((size_t)b * H_ + h) * DK_ + dk) * S_ + s;
          ((u16*)out)[addr] = f2bf(val);
        }
      }
    }
  }
}

// ---------------------------------------------------------------------------
// Flash attention: grid (S/64, B*H). 4 waves/block, 16 q-rows per wave.
// Qh,Kh: [B,H,S,DK] bf16;  Vt: [B,H,DK,S] bf16;  AO: [B,S,D] bf16.
__global__ __launch_bounds__(256, 2) void attn64(
    const u16* __restrict__ Qh, const u16* __restrict__ Kh,
    const u16* __restrict__ Vt, u16* __restrict__ AO) {
  __shared__ __align__(16) u16 P_lds[4][16 * 64];
  const int t = threadIdx.x, lane = t & 63, wave = t >> 6;
  const int bh = blockIdx.y;
  const int q0 = blockIdx.x * 64 + wave * 16;
  const u16* Qp = Qh + (size_t)bh * S_ * DK_;
  const u16* Kp = Kh + (size_t)bh * S_ * DK_;
  const u16* Vp = Vt + (size_t)bh * DK_ * S_;
  u16* Pw = &P_lds[wave][0];
  const int l15 = lane & 15, lhi = lane >> 4;

  bf16x8 qf[2];
  qf[0] = ld_bf8(Qp + (size_t)(q0 + l15) * DK_ + lhi * 8);
  qf[1] = ld_bf8(Qp + (size_t)(q0 + l15) * DK_ + 32 + lhi * 8);

  float mrun[4], lrun[4];
  f32x4 acco[4];
#pragma unroll
  for (int r = 0; r < 4; ++r) { mrun[r] = -1e30f; lrun[r] = 0.f; }
#pragma unroll
  for (int nt = 0; nt < 4; ++nt) acco[nt] = (f32x4){0.f, 0.f, 0.f, 0.f};

  const float c1 = 0.125f * 1.44269504088896f;  // scale * log2(e)

  for (int kv = 0; kv < S_; kv += 64) {
    // QK^T: 16x64 score tile per wave, in exp2 domain
    f32x4 z[4];
#pragma unroll
    for (int nt = 0; nt < 4; ++nt) {
      const u16* kr = Kp + (size_t)(kv + nt * 16 + l15) * DK_ + lhi * 8;
      f32x4 c = {0.f, 0.f, 0.f, 0.f};
      c = mfma16(qf[0], ld_bf8(kr), c);
      c = mfma16(qf[1], ld_bf8(kr + 32), c);
      z[nt] = c * c1;
    }
    // online softmax (rows (lhi*4+r), reduce over 16-lane col groups)
#pragma unroll
    for (int r = 0; r < 4; ++r) {
      float m = fmaxf(fmaxf(z[0][r], z[1][r]), fmaxf(z[2][r], z[3][r]));
      m = fmaxf(m, __shfl_xor(m, 1));
      m = fmaxf(m, __shfl_xor(m, 2));
      m = fmaxf(m, __shfl_xor(m, 4));
      m = fmaxf(m, __shfl_xor(m, 8));
      const float mn = fmaxf(mrun[r], m);
      const float alpha = exp2f(mrun[r] - mn);
      mrun[r] = mn;
      float sum = 0.f;
#pragma unroll
      for (int nt = 0; nt < 4; ++nt) {
        const float p = exp2f(z[nt][r] - mn);
        z[nt][r] = p;
        sum += p;
      }
      sum += __shfl_xor(sum, 1);
      sum += __shfl_xor(sum, 2);
      sum += __shfl_xor(sum, 4);
      sum += __shfl_xor(sum, 8);
      lrun[r] = lrun[r] * alpha + sum;
#pragma unroll
      for (int nt = 0; nt < 4; ++nt) acco[nt][r] *= alpha;
    }
    // P -> LDS (bf16, XOR-swizzled rows to kill ds_read_b128 bank conflicts)
#pragma unroll
    for (int nt = 0; nt < 4; ++nt)
#pragma unroll
      for (int r = 0; r < 4; ++r) {
        const int row = lhi * 4 + r;
        const int byteoff = row * 128 + ((((nt * 16 + l15) * 2)) ^ ((row & 7) << 4));
        *(u16*)((char*)Pw + byteoff) = f2bf(z[nt][r]);
      }
    // PV: acco += P * V  (V read from transposed layout: contiguous along kv)
#pragma unroll
    for (int nt = 0; nt < 4; ++nt) {
#pragma unroll
      for (int ks = 0; ks < 2; ++ks) {
        const int ch = ks * 4 + lhi;
        bf16x8 pa = ld_bf8((const u16*)((const char*)Pw + l15 * 128 + ((ch * 16) ^ ((l15 & 7) << 4))));
        bf16x8 vf = ld_bf8(Vp + (size_t)(nt * 16 + l15) * S_ + kv + ks * 32 + lhi * 8);
        acco[nt] = mfma16(pa, vf, acco[nt]);
      }
    }
  }

  const int b = bh >> 4, h = bh & 15;
#pragma unroll
  for (int nt = 0; nt < 4; ++nt)
#pragma unroll
    for (int r = 0; r < 4; ++r) {
      const int s = q0 + lhi * 4 + r;
      const int col = h * DK_ + nt * 16 + l15;
      AO[((size_t)b * S_ + s) * D_ + col] = f2bf(acco[nt][r] / lrun[r]);
    }
}

// ---------------------------------------------------------------------------
extern "C" void kernel_launch(void* const* d_in, const int* in_sizes, int n_in,
                              void* d_out, int out_size, void* d_ws, size_t ws_size,
                              hipStream_t stream) {
  const float* q  = (const float*)d_in[0];
  const float* k  = (const float*)d_in[1];
  const float* v  = (const float*)d_in[2];
  const float* Wq = (const float*)d_in[3];
  const float* bq = (const float*)d_in[4];
  const float* Wk = (const float*)d_in[5];
  const float* bk = (const float*)d_in[6];
  const float* Wv = (const float*)d_in[7];
  const float* bv = (const float*)d_in[8];
  const float* Wo = (const float*)d_in[9];
  const float* bo = (const float*)d_in[10];

  u16* ws  = (u16*)d_ws;          // offsets in u16 units
  u16* qb  = ws;                  // 8388608
  u16* kb  = ws + 8388608;
  u16* vb  = ws + 16777216;
  u16* wqb = ws + 25165824;       // 1048576 each
  u16* wkb = ws + 26214400;
  u16* wvb = ws + 27262976;
  u16* wob = ws + 28311552;
  u16* Qh  = ws + 29360128;       // [B,H,S,DK]
  u16* Kh  = ws + 37748736;
  u16* Vt  = ws + 46137344;       // [B,H,DK,S]
  u16* AO  = ws + 54525952;       // [B,S,D]

  cast_bf16_all<<<14336, 256, 0, stream>>>(q, k, v, Wq, Wk, Wv, Wo, ws);

  dim3 g(64, 8);
  gemm_bt<<<g, 256, 0, stream>>>(qb, wqb, bq, Qh, 8192, 1024, 1024, 0);
  gemm_bt<<<g, 256, 0, stream>>>(kb, wkb, bk, Kh, 8192, 1024, 1024, 0);
  gemm_bt<<<g, 256, 0, stream>>>(vb, wvb, bv, Vt, 8192, 1024, 1024, 1);

  attn64<<<dim3(32, 64), 256, 0, stream>>>(Qh, Kh, Vt, AO);

  gemm_bt<<<g, 256, 0, stream>>>(AO, wob, bo, d_out, 8192, 1024, 1024, 2);
}

// Round 2
// 555.140 us; speedup vs baseline: 1.2897x; 1.2897x over previous
//
#include <hip/hip_runtime.h>
#include <cstdint>

#define B_ 4
#define S_ 2048
#define D_ 1024
#define H_ 16
#define DK_ 64

typedef unsigned short u16;
typedef __bf16 bf16x8 __attribute__((ext_vector_type(8)));
typedef float f32x4 __attribute__((ext_vector_type(4)));
typedef float f32x16 __attribute__((ext_vector_type(16)));
typedef u16 u16x8 __attribute__((ext_vector_type(8)));
typedef unsigned u32x4 __attribute__((ext_vector_type(4)));

__device__ __forceinline__ u16 f2bf(float f) {
  union { float f; unsigned u; } x; x.f = f;
  unsigned r = (x.u + 0x7fffu + ((x.u >> 16) & 1u)) >> 16;  // RNE
  return (u16)r;
}

__device__ __forceinline__ bf16x8 ld_bf8(const u16* p) {
  u16x8 v = *(const u16x8*)p;
  return __builtin_bit_cast(bf16x8, v);
}

__device__ __forceinline__ f32x4 mfma16(bf16x8 a, bf16x8 b, f32x4 c) {
  return __builtin_amdgcn_mfma_f32_16x16x32_bf16(a, b, c, 0, 0, 0);
}
__device__ __forceinline__ f32x16 mfma32(bf16x8 a, bf16x8 b, f32x16 c) {
  return __builtin_amdgcn_mfma_f32_32x32x16_bf16(a, b, c, 0, 0, 0);
}

// packed f32->bf16 pair: lo16 = bf16(a), hi16 = bf16(b)
__device__ __forceinline__ unsigned cvtpk(float a, float b) {
  unsigned r;
  asm("v_cvt_pk_bf16_f32 %0, %1, %2" : "=v"(r) : "v"(a), "v"(b));
  return r;
}
// swap a.lanes[32:63] <-> b.lanes[0:31]
__device__ __forceinline__ void plswap(unsigned& a, unsigned& b) {
  asm("v_permlane32_swap_b32 %0, %1" : "+v"(a), "+v"(b));
}

// async global->LDS, 16B per lane; dest is wave-uniform base + lane*16 (linear)
__device__ __forceinline__ void gload_lds16(const void* g, void* l) {
  __builtin_amdgcn_global_load_lds(
      (__attribute__((address_space(1))) void*)(void*)g,
      (__attribute__((address_space(3))) void*)l, 16, 0, 0);
}

// ---------------------------------------------------------------------------
// fp32 -> bf16 cast of q,k,v,Wq,Wk,Wv,Wo into workspace. 8 elems/thread.
__global__ void cast_bf16_all(const float* __restrict__ q, const float* __restrict__ k,
                              const float* __restrict__ v, const float* __restrict__ wq,
                              const float* __restrict__ wk, const float* __restrict__ wv,
                              const float* __restrict__ wo, u16* __restrict__ ws) {
  const size_t u = (size_t)blockIdx.x * blockDim.x + threadIdx.x;
  const float* src;
  size_t dstoff, rel;
  if (u < 3145728) {
    const size_t which = u >> 20;
    rel = u & 1048575;
    src = (which == 0) ? q : ((which == 1) ? k : v);
    dstoff = which * 8388608;
  } else {
    const size_t w = u - 3145728;
    const size_t which = w >> 17;
    rel = w & 131071;
    src = (which == 0) ? wq : ((which == 1) ? wk : ((which == 2) ? wv : wo));
    dstoff = 25165824 + which * 1048576;
  }
  const float4* s4 = (const float4*)(src + rel * 8);
  float4 a = s4[0], b = s4[1];
  u16x8 o;
  o[0] = f2bf(a.x); o[1] = f2bf(a.y); o[2] = f2bf(a.z); o[3] = f2bf(a.w);
  o[4] = f2bf(b.x); o[5] = f2bf(b.y); o[6] = f2bf(b.z); o[7] = f2bf(b.w);
  *(u16x8*)(ws + dstoff + rel * 8) = o;
}

// ---------------------------------------------------------------------------
// C[M,N] = A[M,K] * W[N,K]^T + bias, bf16 inputs, 128x128 tile, BK=64.
// mode 0: write bf16 to [B,H,S,DK];  mode 1: bf16 to [B,H,DK,S];  mode 2: fp32 [M,N]
__global__ __launch_bounds__(256, 2) void gemm_bt(
    const u16* __restrict__ A, const u16* __restrict__ W,
    const float* __restrict__ bias, void* __restrict__ out,
    int M, int N, int K, int mode) {
  __shared__ __align__(16) u16 sA[128 * 64];
  __shared__ __align__(16) u16 sB[128 * 64];
  const int t = threadIdx.x;
  const int lane = t & 63;
  const int wave = t >> 6;
  const int wr = (wave >> 1) * 64, wc = (wave & 1) * 64;
  const int m0 = blockIdx.x * 128, n0 = blockIdx.y * 128;
  const int l15 = lane & 15, lhi = lane >> 4;

  f32x4 acc[4][4];
#pragma unroll
  for (int i = 0; i < 4; ++i)
#pragma unroll
    for (int j = 0; j < 4; ++j) acc[i][j] = (f32x4){0.f, 0.f, 0.f, 0.f};

  const int sr = t >> 3;
  const int slot = t & 7;

  for (int kt = 0; kt < K; kt += 64) {
#pragma unroll
    for (int i = 0; i < 4; ++i) {
      const int r = i * 32 + sr;
      const int c = slot ^ (r & 7);
      gload_lds16(A + (size_t)(m0 + r) * K + kt + c * 8, (char*)sA + (i * 4096 + t * 16));
      gload_lds16(W + (size_t)(n0 + r) * K + kt + c * 8, (char*)sB + (i * 4096 + t * 16));
    }
    __syncthreads();

    bf16x8 af[4][2], bfr[4][2];
#pragma unroll
    for (int mt = 0; mt < 4; ++mt) {
      const int r = wr + mt * 16 + l15;
#pragma unroll
      for (int ks = 0; ks < 2; ++ks) {
        const int ch = ks * 4 + lhi;
        af[mt][ks] = ld_bf8((const u16*)((const char*)sA + r * 128 + ((ch ^ (r & 7)) * 16)));
      }
    }
#pragma unroll
    for (int nt = 0; nt < 4; ++nt) {
      const int r = wc + nt * 16 + l15;
#pragma unroll
      for (int ks = 0; ks < 2; ++ks) {
        const int ch = ks * 4 + lhi;
        bfr[nt][ks] = ld_bf8((const u16*)((const char*)sB + r * 128 + ((ch ^ (r & 7)) * 16)));
      }
    }
#pragma unroll
    for (int mt = 0; mt < 4; ++mt)
#pragma unroll
      for (int nt = 0; nt < 4; ++nt) {
        acc[mt][nt] = mfma16(af[mt][0], bfr[nt][0], acc[mt][nt]);
        acc[mt][nt] = mfma16(af[mt][1], bfr[nt][1], acc[mt][nt]);
      }
    __syncthreads();
  }

  float bv[4];
#pragma unroll
  for (int nt = 0; nt < 4; ++nt) bv[nt] = bias[n0 + wc + nt * 16 + l15];

#pragma unroll
  for (int mt = 0; mt < 4; ++mt) {
#pragma unroll
    for (int nt = 0; nt < 4; ++nt) {
#pragma unroll
      for (int r = 0; r < 4; ++r) {
        const int gm = m0 + wr + mt * 16 + lhi * 4 + r;
        const int gn = n0 + wc + nt * 16 + l15;
        const float val = acc[mt][nt][r] + bv[nt];
        if (mode == 2) {
          ((float*)out)[(size_t)gm * N + gn] = val;
        } else {
          const int b = gm >> 11, s = gm & 2047, h = gn >> 6, dk = gn & 63;
          size_t addr;
          if (mode == 0) addr = (((size_t)b * H_ + h) * S_ + s) * DK_ + dk;
          else           addr = (((size_t)b * H_ + h) * DK_ + dk) * S_ + s;
          ((u16*)out)[addr] = f2bf(val);
        }
      }
    }
  }
}

// ---------------------------------------------------------------------------
// Flash attention, swapped-operand form. grid (S/128, B*H), 4 waves, 32 q/wave.
// Qh,Kh: [B,H,S,DK] bf16;  Vt: [B,H,DK,S] bf16;  AO: [B,S,D] bf16.
// QK^T: mfma32(K_frag, Q_frag) -> St[kv][q], col=lane&31=q (P-row lane-local).
// PV:   mfma32(Vt_frag, P_frag) -> Ot[d][q], col=q -> alpha is per-lane scalar.
__global__ __launch_bounds__(256) void attn_swapped(
    const u16* __restrict__ Qh, const u16* __restrict__ Kh,
    const u16* __restrict__ Vt, u16* __restrict__ AO) {
  __shared__ __align__(16) char obuf[4][4096];  // per-wave 32x64 bf16, XOR-swizzled
  const int t = threadIdx.x, lane = t & 63, wave = t >> 6;
  const int l31 = lane & 31, hi = lane >> 5;
  const int bh = blockIdx.y;
  const int q0 = blockIdx.x * 128 + wave * 32;
  const u16* Qp = Qh + (size_t)bh * S_ * DK_;
  const u16* Kp = Kh + (size_t)bh * S_ * DK_;
  const u16* Vp = Vt + (size_t)bh * DK_ * S_;

  // Q fragments (B operand): col q = l31, k = ks*16 + hi*8 + j
  bf16x8 qf[4];
  const u16* qrow = Qp + (size_t)(q0 + l31) * DK_ + hi * 8;
#pragma unroll
  for (int ks = 0; ks < 4; ++ks) qf[ks] = ld_bf8(qrow + ks * 16);

  f32x16 accA = {0}, accB = {0};
  float mrun = -1e30f, lrun = 0.f;
  const float sc = 0.125f * 1.44269504088896f;  // scale * log2(e)
  const float THR = 44.3614f;                   // 8 / sc (defer-max, T13)

#define MAKE_FRAG(zv, r0, out)                        \
  { unsigned w0 = cvtpk(zv[r0 + 0], zv[r0 + 1]);      \
    unsigned w1 = cvtpk(zv[r0 + 2], zv[r0 + 3]);      \
    unsigned w2 = cvtpk(zv[r0 + 4], zv[r0 + 5]);      \
    unsigned w3 = cvtpk(zv[r0 + 6], zv[r0 + 7]);      \
    plswap(w0, w2); plswap(w1, w3);                   \
    u32x4 ww = {w0, w1, w2, w3};                      \
    out = __builtin_bit_cast(bf16x8, ww); }

  for (int kv = 0; kv < S_; kv += 64) {
    // ---- QK^T: two 32-kv subtiles, A = K rows (row=l31=kv, k=hi*8+j)
    f32x16 z0 = {0}, z1 = {0};
    const u16* krow0 = Kp + (size_t)(kv + l31) * DK_ + hi * 8;
    const u16* krow1 = krow0 + 32 * DK_;
#pragma unroll
    for (int ks = 0; ks < 4; ++ks) z0 = mfma32(ld_bf8(krow0 + ks * 16), qf[ks], z0);
#pragma unroll
    for (int ks = 0; ks < 4; ++ks) z1 = mfma32(ld_bf8(krow1 + ks * 16), qf[ks], z1);

    // ---- online softmax: lane owns P-row for q = l31 (split across lane^32)
    float pmax = z0[0];
#pragma unroll
    for (int i = 1; i < 16; ++i) pmax = fmaxf(pmax, z0[i]);
#pragma unroll
    for (int i = 0; i < 16; ++i) pmax = fmaxf(pmax, z1[i]);
    pmax = fmaxf(pmax, __shfl_xor(pmax, 32));

    if (!__all(pmax <= mrun + THR)) {   // defer-max: rescale only when needed
      const float mnew = fmaxf(mrun, pmax);
      const float alpha = exp2f((mrun - mnew) * sc);
      lrun *= alpha;
#pragma unroll
      for (int i = 0; i < 16; ++i) { accA[i] *= alpha; accB[i] *= alpha; }
      mrun = mnew;
    }
    const float msc = mrun * sc;
    float psum = 0.f;
#pragma unroll
    for (int i = 0; i < 16; ++i) { const float p = exp2f(fmaf(z0[i], sc, -msc)); z0[i] = p; psum += p; }
#pragma unroll
    for (int i = 0; i < 16; ++i) { const float p = exp2f(fmaf(z1[i], sc, -msc)); z1[i] = p; psum += p; }
    psum += __shfl_xor(psum, 32);
    lrun += psum;

    // ---- PV: A = V^T rows (row=l31=d, k=hi*8+j), B = P frags (col=q)
    const u16* vrowA = Vp + (size_t)l31 * S_ + kv + hi * 8;
    const u16* vrowB = vrowA + (size_t)32 * S_;
    bf16x8 pf;
    MAKE_FRAG(z0, 0, pf);
    accA = mfma32(ld_bf8(vrowA), pf, accA);
    accB = mfma32(ld_bf8(vrowB), pf, accB);
    MAKE_FRAG(z0, 8, pf);
    accA = mfma32(ld_bf8(vrowA + 16), pf, accA);
    accB = mfma32(ld_bf8(vrowB + 16), pf, accB);
    MAKE_FRAG(z1, 0, pf);
    accA = mfma32(ld_bf8(vrowA + 32), pf, accA);
    accB = mfma32(ld_bf8(vrowB + 32), pf, accB);
    MAKE_FRAG(z1, 8, pf);
    accA = mfma32(ld_bf8(vrowA + 48), pf, accA);
    accB = mfma32(ld_bf8(vrowB + 48), pf, accB);
  }

  // ---- epilogue: normalize, transpose O^T->O via per-wave swizzled LDS
  const float inv = 1.0f / lrun;
  char* ob = obuf[wave];
  const int swz = (l31 & 7) << 4;
#pragma unroll
  for (int r = 0; r < 16; r += 2) {
    const int d = (r & 3) + 8 * (r >> 2) + 4 * hi;  // rows d, d+1
    const unsigned wA = cvtpk(accA[r] * inv, accA[r + 1] * inv);
    const unsigned wB = cvtpk(accB[r] * inv, accB[r + 1] * inv);
    *(unsigned*)(ob + l31 * 128 + ((2 * d) ^ swz)) = wA;
    *(unsigned*)(ob + l31 * 128 + ((2 * (d + 32)) ^ swz)) = wB;
  }
  __syncthreads();
  const int bb = bh >> 4, hh = bh & 15;
  const int q = lane >> 1, half = lane & 1;
  u16* dst = AO + ((size_t)bb * S_ + q0 + q) * D_ + hh * 64;
  const int rswz = (q & 7) << 4;
#pragma unroll
  for (int p = 0; p < 4; ++p) {
    const int ds0 = half * 32 + p * 8;
    u16x8 val = *(u16x8*)(ob + q * 128 + ((2 * ds0) ^ rswz));
    *(u16x8*)(dst + ds0) = val;
  }
}

// ---------------------------------------------------------------------------
extern "C" void kernel_launch(void* const* d_in, const int* in_sizes, int n_in,
                              void* d_out, int out_size, void* d_ws, size_t ws_size,
                              hipStream_t stream) {
  const float* q  = (const float*)d_in[0];
  const float* k  = (const float*)d_in[1];
  const float* v  = (const float*)d_in[2];
  const float* Wq = (const float*)d_in[3];
  const float* bq = (const float*)d_in[4];
  const float* Wk = (const float*)d_in[5];
  const float* bk = (const float*)d_in[6];
  const float* Wv = (const float*)d_in[7];
  const float* bv = (const float*)d_in[8];
  const float* Wo = (const float*)d_in[9];
  const float* bo = (const float*)d_in[10];

  u16* ws  = (u16*)d_ws;
  u16* qb  = ws;
  u16* kb  = ws + 8388608;
  u16* vb  = ws + 16777216;
  u16* wqb = ws + 25165824;
  u16* wkb = ws + 26214400;
  u16* wvb = ws + 27262976;
  u16* wob = ws + 28311552;
  u16* Qh  = ws + 29360128;       // [B,H,S,DK]
  u16* Kh  = ws + 37748736;
  u16* Vt  = ws + 46137344;       // [B,H,DK,S]
  u16* AO  = ws + 54525952;       // [B,S,D]

  cast_bf16_all<<<14336, 256, 0, stream>>>(q, k, v, Wq, Wk, Wv, Wo, ws);

  dim3 g(64, 8);
  gemm_bt<<<g, 256, 0, stream>>>(qb, wqb, bq, Qh, 8192, 1024, 1024, 0);
  gemm_bt<<<g, 256, 0, stream>>>(kb, wkb, bk, Kh, 8192, 1024, 1024, 0);
  gemm_bt<<<g, 256, 0, stream>>>(vb, wvb, bv, Vt, 8192, 1024, 1024, 1);

  attn_swapped<<<dim3(16, 64), 256, 0, stream>>>(Qh, Kh, Vt, AO);

  gemm_bt<<<g, 256, 0, stream>>>(AO, wob, bo, d_out, 8192, 1024, 1024, 2);
}

// Round 3
// 396.083 us; speedup vs baseline: 1.8076x; 1.4016x over previous
//
#include <hip/hip_runtime.h>
#include <cstdint>

#define B_ 4
#define S_ 2048
#define D_ 1024
#define H_ 16
#define DK_ 64

typedef unsigned short u16;
typedef __bf16 bf16x8 __attribute__((ext_vector_type(8)));
typedef float f32x4 __attribute__((ext_vector_type(4)));
typedef float f32x16 __attribute__((ext_vector_type(16)));
typedef u16 u16x8 __attribute__((ext_vector_type(8)));
typedef unsigned u32x4 __attribute__((ext_vector_type(4)));

__device__ __forceinline__ u16 f2bf(float f) {
  union { float f; unsigned u; } x; x.f = f;
  unsigned r = (x.u + 0x7fffu + ((x.u >> 16) & 1u)) >> 16;  // RNE
  return (u16)r;
}

__device__ __forceinline__ bf16x8 ld_bf8(const u16* p) {
  u16x8 v = *(const u16x8*)p;
  return __builtin_bit_cast(bf16x8, v);
}

__device__ __forceinline__ f32x4 mfma16(bf16x8 a, bf16x8 b, f32x4 c) {
  return __builtin_amdgcn_mfma_f32_16x16x32_bf16(a, b, c, 0, 0, 0);
}
__device__ __forceinline__ f32x16 mfma32(bf16x8 a, bf16x8 b, f32x16 c) {
  return __builtin_amdgcn_mfma_f32_32x32x16_bf16(a, b, c, 0, 0, 0);
}

// packed f32->bf16 pair: lo16 = bf16(a), hi16 = bf16(b)
__device__ __forceinline__ unsigned cvtpk(float a, float b) {
  unsigned r;
  asm("v_cvt_pk_bf16_f32 %0, %1, %2" : "=v"(r) : "v"(a), "v"(b));
  return r;
}
// swap a.lanes[32:63] <-> b.lanes[0:31]
__device__ __forceinline__ void plswap(unsigned& a, unsigned& b) {
  asm("v_permlane32_swap_b32 %0, %1" : "+v"(a), "+v"(b));
}

// async global->LDS, 16B per lane; dest is wave-uniform base + lane*16 (linear)
__device__ __forceinline__ void gload_lds16(const void* g, void* l) {
  __builtin_amdgcn_global_load_lds(
      (__attribute__((address_space(1))) void*)(void*)g,
      (__attribute__((address_space(3))) void*)l, 16, 0, 0);
}

// ---------------------------------------------------------------------------
// fp32 -> bf16 cast of q,k,v,Wq,Wk,Wv,Wo into workspace. 8 elems/thread.
__global__ void cast_bf16_all(const float* __restrict__ q, const float* __restrict__ k,
                              const float* __restrict__ v, const float* __restrict__ wq,
                              const float* __restrict__ wk, const float* __restrict__ wv,
                              const float* __restrict__ wo, u16* __restrict__ ws) {
  const size_t u = (size_t)blockIdx.x * blockDim.x + threadIdx.x;
  const float* src;
  size_t dstoff, rel;
  if (u < 3145728) {
    const size_t which = u >> 20;
    rel = u & 1048575;
    src = (which == 0) ? q : ((which == 1) ? k : v);
    dstoff = which * 8388608;
  } else {
    const size_t w = u - 3145728;
    const size_t which = w >> 17;
    rel = w & 131071;
    src = (which == 0) ? wq : ((which == 1) ? wk : ((which == 2) ? wv : wo));
    dstoff = 25165824 + which * 1048576;
  }
  const float4* s4 = (const float4*)(src + rel * 8);
  float4 a = s4[0], b = s4[1];
  u16x8 o;
  o[0] = f2bf(a.x); o[1] = f2bf(a.y); o[2] = f2bf(a.z); o[3] = f2bf(a.w);
  o[4] = f2bf(b.x); o[5] = f2bf(b.y); o[6] = f2bf(b.z); o[7] = f2bf(b.w);
  *(u16x8*)(ws + dstoff + rel * 8) = o;
}

// ---------------------------------------------------------------------------
// C[M,N] = A[M,K] * W[N,K]^T + bias, bf16 inputs, 128x128 tile, BK=64.
// mode 0: write bf16 to [B,H,S,DK];  mode 1: bf16 to [B,H,DK,S];  mode 2: fp32 [M,N]
__global__ __launch_bounds__(256, 2) void gemm_bt(
    const u16* __restrict__ A, const u16* __restrict__ W,
    const float* __restrict__ bias, void* __restrict__ out,
    int M, int N, int K, int mode) {
  __shared__ __align__(16) u16 sA[128 * 64];
  __shared__ __align__(16) u16 sB[128 * 64];
  const int t = threadIdx.x;
  const int lane = t & 63;
  const int wave = t >> 6;
  const int wr = (wave >> 1) * 64, wc = (wave & 1) * 64;
  const int m0 = blockIdx.x * 128, n0 = blockIdx.y * 128;
  const int l15 = lane & 15, lhi = lane >> 4;

  f32x4 acc[4][4];
#pragma unroll
  for (int i = 0; i < 4; ++i)
#pragma unroll
    for (int j = 0; j < 4; ++j) acc[i][j] = (f32x4){0.f, 0.f, 0.f, 0.f};

  const int sr = t >> 3;
  const int slot = t & 7;

  for (int kt = 0; kt < K; kt += 64) {
#pragma unroll
    for (int i = 0; i < 4; ++i) {
      const int r = i * 32 + sr;
      const int c = slot ^ (r & 7);
      gload_lds16(A + (size_t)(m0 + r) * K + kt + c * 8, (char*)sA + (i * 4096 + t * 16));
      gload_lds16(W + (size_t)(n0 + r) * K + kt + c * 8, (char*)sB + (i * 4096 + t * 16));
    }
    __syncthreads();

    bf16x8 af[4][2], bfr[4][2];
#pragma unroll
    for (int mt = 0; mt < 4; ++mt) {
      const int r = wr + mt * 16 + l15;
#pragma unroll
      for (int ks = 0; ks < 2; ++ks) {
        const int ch = ks * 4 + lhi;
        af[mt][ks] = ld_bf8((const u16*)((const char*)sA + r * 128 + ((ch ^ (r & 7)) * 16)));
      }
    }
#pragma unroll
    for (int nt = 0; nt < 4; ++nt) {
      const int r = wc + nt * 16 + l15;
#pragma unroll
      for (int ks = 0; ks < 2; ++ks) {
        const int ch = ks * 4 + lhi;
        bfr[nt][ks] = ld_bf8((const u16*)((const char*)sB + r * 128 + ((ch ^ (r & 7)) * 16)));
      }
    }
#pragma unroll
    for (int mt = 0; mt < 4; ++mt)
#pragma unroll
      for (int nt = 0; nt < 4; ++nt) {
        acc[mt][nt] = mfma16(af[mt][0], bfr[nt][0], acc[mt][nt]);
        acc[mt][nt] = mfma16(af[mt][1], bfr[nt][1], acc[mt][nt]);
      }
    __syncthreads();
  }

  float bv[4];
#pragma unroll
  for (int nt = 0; nt < 4; ++nt) bv[nt] = bias[n0 + wc + nt * 16 + l15];

#pragma unroll
  for (int mt = 0; mt < 4; ++mt) {
#pragma unroll
    for (int nt = 0; nt < 4; ++nt) {
#pragma unroll
      for (int r = 0; r < 4; ++r) {
        const int gm = m0 + wr + mt * 16 + lhi * 4 + r;
        const int gn = n0 + wc + nt * 16 + l15;
        const float val = acc[mt][nt][r] + bv[nt];
        if (mode == 2) {
          ((float*)out)[(size_t)gm * N + gn] = val;
        } else {
          const int b = gm >> 11, s = gm & 2047, h = gn >> 6, dk = gn & 63;
          size_t addr;
          if (mode == 0) addr = (((size_t)b * H_ + h) * S_ + s) * DK_ + dk;
          else           addr = (((size_t)b * H_ + h) * DK_ + dk) * S_ + s;
          ((u16*)out)[addr] = f2bf(val);
        }
      }
    }
  }
}

// ---------------------------------------------------------------------------
// Flash attention, swapped-operand + LDS-staged K/V, 2-phase prefetch.
// grid 1024 blocks (XCD-swizzled), 4 waves, 32 q/wave (128 q/block).
// K tile 64x64 bf16 (8KB), V^T tile 64x64 bf16 (8KB), double-buffered (32KB).
// LDS slot layout (16B slots): slot = ks*128 + sub*64 + lane  where the
// fragment (row = sub*32 + l31, chunk = 2ks + hi) lives at that slot.
// -> every ds_read_b128 is 64 contiguous slots (conflict-free); staging is
// linear dest (slot = i*256 + t) with the permutation applied to the
// per-lane GLOBAL source address (rule 21).
__global__ __launch_bounds__(256) void attn_pipe(
    const u16* __restrict__ Qh, const u16* __restrict__ Kh,
    const u16* __restrict__ Vt, u16* __restrict__ AO) {
  __shared__ __align__(16) char smem[32768];  // [2][ K 8KB | V 8KB ]
  const int t = threadIdx.x, lane = t & 63, wave = t >> 6;
  const int l31 = lane & 31, hi = lane >> 5;

  // XCD swizzle: 1024 blocks, 8 XCDs -> 128 consecutive per XCD = 8 whole heads
  const int bid = blockIdx.x;
  const int id = (bid & 7) * 128 + (bid >> 3);
  const int bh = id >> 4;             // head index 0..63
  const int q0 = (id & 15) * 128 + wave * 32;

  const u16* Qp = Qh + (size_t)bh * S_ * DK_;
  const u16* Kp = Kh + (size_t)bh * S_ * DK_;
  const u16* Vp = Vt + (size_t)bh * DK_ * S_;

  // staging slot decode (slots s0 = t, s1 = 256+t):
  //   r = ((s>>6)&1)*32 + (s&31);  c = ((s>>7)&3)*2 + ((s>>5)&1)
  const int s1 = 256 + t;
  const int r0 = ((t >> 6) & 1) * 32 + (t & 31), c0 = ((t >> 7) & 3) * 2 + ((t >> 5) & 1);
  const int r1 = ((s1 >> 6) & 1) * 32 + (s1 & 31), c1 = ((s1 >> 7) & 3) * 2 + ((s1 >> 5) & 1);

#define STAGE_KV(buf, kv0)                                                      \
  { char* bK = smem + (buf) * 16384;                                            \
    char* bV = bK + 8192;                                                       \
    gload_lds16(Kp + (size_t)((kv0) + r0) * DK_ + c0 * 8, bK + t * 16);         \
    gload_lds16(Kp + (size_t)((kv0) + r1) * DK_ + c1 * 8, bK + 4096 + t * 16);  \
    gload_lds16(Vp + (size_t)r0 * S_ + (kv0) + c0 * 8, bV + t * 16);            \
    gload_lds16(Vp + (size_t)r1 * S_ + (kv0) + c1 * 8, bV + 4096 + t * 16); }

  // Q fragments (B operand): col q = l31, k = ks*16 + hi*8 + j
  bf16x8 qf[4];
  {
    const u16* qrow = Qp + (size_t)(q0 + l31) * DK_ + hi * 8;
#pragma unroll
    for (int ks = 0; ks < 4; ++ks) qf[ks] = ld_bf8(qrow + ks * 16);
  }

  STAGE_KV(0, 0);
  __syncthreads();

  f32x16 accA = {0}, accB = {0};
  float mrun = -1e30f, lrun = 0.f;
  const float sc = 0.125f * 1.44269504088896f;  // scale * log2(e)
  const float THR = 44.3614f;                   // 8 / sc (defer-max, T13)

#define MAKE_FRAG(zv, r0_, out)                       \
  { unsigned w0 = cvtpk(zv[r0_ + 0], zv[r0_ + 1]);    \
    unsigned w1 = cvtpk(zv[r0_ + 2], zv[r0_ + 3]);    \
    unsigned w2 = cvtpk(zv[r0_ + 4], zv[r0_ + 5]);    \
    unsigned w3 = cvtpk(zv[r0_ + 6], zv[r0_ + 7]);    \
    plswap(w0, w2); plswap(w1, w3);                   \
    u32x4 ww = {w0, w1, w2, w3};                      \
    out = __builtin_bit_cast(bf16x8, ww); }

  int cur = 0;
  for (int kv = 0; kv < S_; kv += 64) {
    // issue next tile's staging FIRST (overlaps with this tile's compute)
    if (kv + 64 < S_) STAGE_KV(cur ^ 1, kv + 64);

    const char* cK = smem + cur * 16384;
    const char* cV = cK + 8192;
    const int loff = lane * 16;

    // ---- QK^T: z0 (kv rows 0-31), z1 (rows 32-63); frags from LDS
    f32x16 z0 = {0}, z1 = {0};
    __builtin_amdgcn_s_setprio(1);
#pragma unroll
    for (int ks = 0; ks < 4; ++ks) {
      z0 = mfma32(ld_bf8((const u16*)(cK + ks * 2048 + loff)), qf[ks], z0);
      z1 = mfma32(ld_bf8((const u16*)(cK + ks * 2048 + 1024 + loff)), qf[ks], z1);
    }
    __builtin_amdgcn_s_setprio(0);

    // ---- online softmax: lane owns P-row for q = l31 (split across lane^32)
    float m8[8];
#pragma unroll
    for (int i = 0; i < 8; ++i)
      m8[i] = fmaxf(fmaxf(z0[2 * i], z0[2 * i + 1]), fmaxf(z1[2 * i], z1[2 * i + 1]));
    float pmax = fmaxf(fmaxf(fmaxf(m8[0], m8[1]), fmaxf(m8[2], m8[3])),
                       fmaxf(fmaxf(m8[4], m8[5]), fmaxf(m8[6], m8[7])));
    pmax = fmaxf(pmax, __shfl_xor(pmax, 32));

    if (!__all(pmax <= mrun + THR)) {   // defer-max: rescale only when needed
      const float mnew = fmaxf(mrun, pmax);
      const float alpha = exp2f((mrun - mnew) * sc);
      lrun *= alpha;
#pragma unroll
      for (int i = 0; i < 16; ++i) { accA[i] *= alpha; accB[i] *= alpha; }
      mrun = mnew;
    }
    const float msc = mrun * sc;
#pragma unroll
    for (int i = 0; i < 16; ++i) z0[i] = exp2f(fmaf(z0[i], sc, -msc));
#pragma unroll
    for (int i = 0; i < 16; ++i) z1[i] = exp2f(fmaf(z1[i], sc, -msc));
    float p8[8];
#pragma unroll
    for (int i = 0; i < 8; ++i)
      p8[i] = (z0[2 * i] + z0[2 * i + 1]) + (z1[2 * i] + z1[2 * i + 1]);
    float psum = ((p8[0] + p8[1]) + (p8[2] + p8[3])) + ((p8[4] + p8[5]) + (p8[6] + p8[7]));
    psum += __shfl_xor(psum, 32);
    lrun += psum;

    // ---- PV: A = V^T frags from LDS (rows d: sub=0 -> accA, sub=1 -> accB)
    bf16x8 pf;
    __builtin_amdgcn_s_setprio(1);
    MAKE_FRAG(z0, 0, pf);
    accA = mfma32(ld_bf8((const u16*)(cV + 0 * 2048 + loff)), pf, accA);
    accB = mfma32(ld_bf8((const u16*)(cV + 0 * 2048 + 1024 + loff)), pf, accB);
    MAKE_FRAG(z0, 8, pf);
    accA = mfma32(ld_bf8((const u16*)(cV + 1 * 2048 + loff)), pf, accA);
    accB = mfma32(ld_bf8((const u16*)(cV + 1 * 2048 + 1024 + loff)), pf, accB);
    MAKE_FRAG(z1, 0, pf);
    accA = mfma32(ld_bf8((const u16*)(cV + 2 * 2048 + loff)), pf, accA);
    accB = mfma32(ld_bf8((const u16*)(cV + 2 * 2048 + 1024 + loff)), pf, accB);
    MAKE_FRAG(z1, 8, pf);
    accA = mfma32(ld_bf8((const u16*)(cV + 3 * 2048 + loff)), pf, accA);
    accB = mfma32(ld_bf8((const u16*)(cV + 3 * 2048 + 1024 + loff)), pf, accB);
    __builtin_amdgcn_s_setprio(0);

    __syncthreads();   // drains vmcnt (staging done) + lgkm; flips buffer
    cur ^= 1;
  }

  // ---- epilogue: normalize, transpose O^T->O via per-wave swizzled LDS
  const float inv = 1.0f / lrun;
  char* ob = smem + wave * 4096;   // reuse staging LDS (all reads done)
  const int swz = (l31 & 7) << 4;
#pragma unroll
  for (int r = 0; r < 16; r += 2) {
    const int d = (r & 3) + 8 * (r >> 2) + 4 * hi;  // rows d, d+1
    const unsigned wA = cvtpk(accA[r] * inv, accA[r + 1] * inv);
    const unsigned wB = cvtpk(accB[r] * inv, accB[r + 1] * inv);
    *(unsigned*)(ob + l31 * 128 + ((2 * d) ^ swz)) = wA;
    *(unsigned*)(ob + l31 * 128 + ((2 * (d + 32)) ^ swz)) = wB;
  }
  __syncthreads();
  const int bb = bh >> 4, hh = bh & 15;
  const int q = lane >> 1, half = lane & 1;
  u16* dst = AO + ((size_t)bb * S_ + q0 + q) * D_ + hh * 64;
  const int rswz = (q & 7) << 4;
#pragma unroll
  for (int p = 0; p < 4; ++p) {
    const int ds0 = half * 32 + p * 8;
    u16x8 val = *(u16x8*)(ob + q * 128 + ((2 * ds0) ^ rswz));
    *(u16x8*)(dst + ds0) = val;
  }
}

// ---------------------------------------------------------------------------
extern "C" void kernel_launch(void* const* d_in, const int* in_sizes, int n_in,
                              void* d_out, int out_size, void* d_ws, size_t ws_size,
                              hipStream_t stream) {
  const float* q  = (const float*)d_in[0];
  const float* k  = (const float*)d_in[1];
  const float* v  = (const float*)d_in[2];
  const float* Wq = (const float*)d_in[3];
  const float* bq = (const float*)d_in[4];
  const float* Wk = (const float*)d_in[5];
  const float* bk = (const float*)d_in[6];
  const float* Wv = (const float*)d_in[7];
  const float* bv = (const float*)d_in[8];
  const float* Wo = (const float*)d_in[9];
  const float* bo = (const float*)d_in[10];

  u16* ws  = (u16*)d_ws;
  u16* qb  = ws;
  u16* kb  = ws + 8388608;
  u16* vb  = ws + 16777216;
  u16* wqb = ws + 25165824;
  u16* wkb = ws + 26214400;
  u16* wvb = ws + 27262976;
  u16* wob = ws + 28311552;
  u16* Qh  = ws + 29360128;       // [B,H,S,DK]
  u16* Kh  = ws + 37748736;
  u16* Vt  = ws + 46137344;       // [B,H,DK,S]
  u16* AO  = ws + 54525952;       // [B,S,D]

  cast_bf16_all<<<14336, 256, 0, stream>>>(q, k, v, Wq, Wk, Wv, Wo, ws);

  dim3 g(64, 8);
  gemm_bt<<<g, 256, 0, stream>>>(qb, wqb, bq, Qh, 8192, 1024, 1024, 0);
  gemm_bt<<<g, 256, 0, stream>>>(kb, wkb, bk, Kh, 8192, 1024, 1024, 0);
  gemm_bt<<<g, 256, 0, stream>>>(vb, wvb, bv, Vt, 8192, 1024, 1024, 1);

  attn_pipe<<<1024, 256, 0, stream>>>(Qh, Kh, Vt, AO);

  gemm_bt<<<g, 256, 0, stream>>>(AO, wob, bo, d_out, 8192, 1024, 1024, 2);
}